// Round 6
// baseline (467.576 us; speedup 1.0000x reference)
//
#include <hip/hip_runtime.h>

typedef unsigned short u16;
typedef unsigned int   u32;
typedef __bf16 bf16;
typedef bf16  bf16x8 __attribute__((ext_vector_type(8)));
typedef float f32x4  __attribute__((ext_vector_type(4)));

__device__ __forceinline__ u16 bf16u(float f) {
    u32 x = __builtin_bit_cast(u32, f);
    x += 0x7fffu + ((x >> 16) & 1u);   // RNE
    return (u16)(x >> 16);
}

__device__ __forceinline__ void gl_lds16(const void* g, void* l) {
    __builtin_amdgcn_global_load_lds(
        (const __attribute__((address_space(1))) u32*)g,
        (__attribute__((address_space(3))) u32*)l, 16, 0, 0);
}

// ---------------- fp32 -> bf16 convert (vectorized) ----------------
__global__ __launch_bounds__(256) void cvt_x_kernel(const float4* __restrict__ in,
                                                    ushort4* __restrict__ out, int n4) {
    int i = blockIdx.x * 256 + threadIdx.x;
    if (i >= n4) return;
    float4 f = in[i];
    ushort4 o;
    o.x = bf16u(f.x); o.y = bf16u(f.y); o.z = bf16u(f.z); o.w = bf16u(f.w);
    out[i] = o;
}

// ---------------- fp32 W[rows][cols] -> bf16 W^T[cols][rows] ----------------
__global__ __launch_bounds__(256) void transp_kernel(const float* __restrict__ W,
                                                     u16* __restrict__ WT,
                                                     int rows, int cols) {
    __shared__ float t[32][33];
    int bx = blockIdx.x * 32, by = blockIdx.y * 32;
    int x = threadIdx.x & 31, y = threadIdx.x >> 5;
#pragma unroll
    for (int i = 0; i < 32; i += 8)
        t[y + i][x] = W[(size_t)(by + y + i) * cols + bx + x];
    __syncthreads();
#pragma unroll
    for (int i = 0; i < 32; i += 8)
        WT[(size_t)(bx + y + i) * rows + by + x] = bf16u(t[x][y + i]);
}

// ====== 256x256 GEMM, BK=32, 4-buffer, read-one-phase-ahead pipeline ========
// C[M][N] = A[M][K] * BT[N][K]^T. 512 thr = 8 waves (2M x 4N), wave 128x64.
// LDS: 4 bufs x (A 256x32 + B 256x32) x 2B = 128 KB. 2 phases per K-tile:
//   (t,a): [issue reads A_t.mh1 | stage A(t+3)] BAR [16 MFMA mh0] VMPUB(t+1) BAR
//   (t,b): [issue reads A_{t+1}.mh0 + B_{t+1} | stage B(t+3)] BAR [16 MFMA mh1] BAR
// Reads for each phase issued one phase EARLY -> overlap MFMA; compiler inserts
// the counted lgkmcnt for the dataflow. vmcnt publish counts derived from
// global stage issue order (A3,B3,A4,B4,...): VM6 steady, VM4/VM0 tail.
// Chunk swizzle: physical 16B-chunk = logical ^ ((row>>1)&3), inverse-applied
// on the global source (linear LDS dest; rule: both-sides-or-neither).
__device__ __forceinline__ void rdA4(const u16* b, int ra, int phys, int mh,
                                     bf16x8 (&f)[4]) {
#pragma unroll
    for (int q = 0; q < 4; q++)
        f[q] = *(const bf16x8*)&b[ra + (((mh << 2) + q) << 9) + phys];
}
__device__ __forceinline__ void rdB4(const u16* b, int rb, int phys,
                                     bf16x8 (&f)[4]) {
#pragma unroll
    for (int q = 0; q < 4; q++)
        f[q] = *(const bf16x8*)&b[rb + (q << 9) + phys];
}
__device__ __forceinline__ void mm16f(f32x4 (&acc)[8][4], int mh,
                                      const bf16x8 (&fa)[4], const bf16x8 (&fb)[4]) {
    __builtin_amdgcn_s_setprio(1);
#pragma unroll
    for (int m = 0; m < 4; m++)
#pragma unroll
        for (int n = 0; n < 4; n++)
            acc[(mh << 2) + m][n] = __builtin_amdgcn_mfma_f32_16x16x32_bf16(
                fa[m], fb[n], acc[(mh << 2) + m][n], 0, 0, 0);
    __builtin_amdgcn_s_setprio(0);
}

#define BAR   __builtin_amdgcn_s_barrier()
#define VM8   asm volatile("s_waitcnt vmcnt(8)" ::: "memory")
#define VM6   asm volatile("s_waitcnt vmcnt(6)" ::: "memory")
#define VM4   asm volatile("s_waitcnt vmcnt(4)" ::: "memory")
#define VM0   asm volatile("s_waitcnt vmcnt(0)" ::: "memory")

__global__ __launch_bounds__(512, 2) void gemm8(
    const u16* __restrict__ A, const u16* __restrict__ BT, void* __restrict__ Cout,
    const float* __restrict__ cosp, const float* __restrict__ sinp,
    int M, int N, int K, int mode)
{
    __shared__ u16 Ld[4][16384];   // per buf: A @0 (8192 u16), B @8192
    const int tid = threadIdx.x;
    const int wid = tid >> 6, lane = tid & 63;
    const int nx = gridDim.x;
    const int nwg = nx * gridDim.y;
    const int orig = blockIdx.y * nx + blockIdx.x;
    const int vid = (orig & 7) * (nwg >> 3) + (orig >> 3);
    const int m0 = (vid / nx) << 8, n0 = (vid % nx) << 8;
    const int wr = wid >> 2, wc = wid & 3;

    // ---- staging: thread covers chunk tid (rows 0..127) and 512+tid (+128) ----
    const int r1 = tid >> 2;                       // row in [0,128)
    const int l1 = (tid & 3) ^ ((r1 >> 1) & 3);    // logical chunk to fetch
    const u16* Asrc = A + (size_t)(m0 + r1) * K + (l1 << 3);
    const u16* Bsrc = BT + (size_t)(n0 + r1) * K + (l1 << 3);
    const size_t h128K = (size_t)128 * K;          // +128 rows: same swizzle
    const int wdb = wid << 9;                      // wave-uniform LDS dest
    const int nt = K >> 5;                         // K-tiles (32-wide); %4==0

#define STA(T, DB) do { if ((T) < nt) { const u16* _s = Asrc + ((size_t)(T) << 5); \
        gl_lds16(_s,         &Ld[DB][wdb]); \
        gl_lds16(_s + h128K, &Ld[DB][4096 + wdb]); } } while (0)
#define STB(T, DB) do { if ((T) < nt) { const u16* _s = Bsrc + ((size_t)(T) << 5); \
        gl_lds16(_s,         &Ld[DB][8192 + wdb]); \
        gl_lds16(_s + h128K, &Ld[DB][12288 + wdb]); } } while (0)
#define VMPUB(t) do { if ((t) + 3 < nt) { VM6; } \
                      else if ((t) + 2 < nt) { VM4; } else { VM0; } } while (0)

    // frag-read addressing: physical chunk = logical(lane>>4) ^ ((row>>1)&3);
    // row = base + m*16 keeps (row>>1)&3 = (lane>>1)&3 (m*16 doesn't touch bits 1-2)
    const int phys = ((lane >> 4) ^ ((lane >> 1) & 3)) << 3;
    const int ra = ((wr << 7) + (lane & 15)) << 5;
    const int rb = ((((wc << 6) + (lane & 15)) << 5)) + 8192;

    f32x4 acc[8][4] = {};
    bf16x8 faA[4], faB[4], fb0[4], fb1[4];

    // prologue: stage tiles 0,1,2 (issue order A0,B0,A1,B1,A2,B2)
    STA(0, 0); STB(0, 0); STA(1, 1); STB(1, 1); STA(2, 2); STB(2, 2);
    VM8;                         // tile 0 landed
    BAR;
    rdA4(&Ld[0][0], ra, phys, 0, faA);
    rdB4(&Ld[0][0], rb, phys, fb0);

#define PH_PAIR(t, D, D2, D3, E, F) do { \
    /* (t,a) */ \
    rdA4(&Ld[D][0], ra, phys, 1, faB); \
    STA((t) + 3, D3); \
    BAR; \
    mm16f(acc, 0, faA, fb##E); \
    VMPUB(t); \
    BAR; \
    /* (t,b) */ \
    if ((t) + 1 < nt) { \
        rdA4(&Ld[D2][0], ra, phys, 0, faA); \
        rdB4(&Ld[D2][0], rb, phys, fb##F); \
    } \
    STB((t) + 3, D3); \
    BAR; \
    mm16f(acc, 1, faB, fb##E); \
    BAR; \
} while (0)

    for (int t = 0; t < nt; t += 4) {
        PH_PAIR(t,     0, 1, 3, 0, 1);
        PH_PAIR(t + 1, 1, 2, 0, 1, 0);
        PH_PAIR(t + 2, 2, 3, 1, 0, 1);
        PH_PAIR(t + 3, 3, 0, 2, 1, 0);
    }
#undef PH_PAIR
#undef STA
#undef STB
#undef VMPUB

    const int colbase = n0 + (wc << 6) + (lane & 15);
    if (mode == 2) {
        float* C = (float*)Cout;
#pragma unroll
        for (int mi = 0; mi < 8; mi++)
#pragma unroll
            for (int r = 0; r < 4; r++) {
                int m = m0 + (wr << 7) + (mi << 4) + ((lane >> 4) << 2) + r;
                float* row = C + (size_t)m * N + colbase;
#pragma unroll
                for (int ni = 0; ni < 4; ni++) row[ni << 4] = acc[mi][ni][r];
            }
    } else if (n0 < 2048) {                   // fused QKV: RoPE region (Q and K)
        u16* C = (u16*)Cout;
#pragma unroll
        for (int mi = 0; mi < 8; mi++)
#pragma unroll
            for (int r = 0; r < 4; r++) {
                int m = m0 + (wr << 7) + (mi << 4) + ((lane >> 4) << 2) + r;
                const float* cb = cosp + ((size_t)m << 6);
                const float* sb = sinp + ((size_t)m << 6);
                u16* row = C + (size_t)m * N + colbase;
#pragma unroll
                for (int ni = 0; ni < 4; ni++) {
                    int d = (ni << 4) + (lane & 15);   // head-dim pos (0..63)
                    float c = cb[d], s = sb[d];
                    float v0 = acc[mi][ni][r];
                    float vr = acc[mi][ni ^ 2][r];     // d +/- 32 partner
                    float o = fmaf(v0, c, (ni < 2 ? -vr : vr) * s);
                    row[ni << 4] = bf16u(o);
                }
            }
    } else {                                  // V region: plain bf16
        u16* C = (u16*)Cout;
#pragma unroll
        for (int mi = 0; mi < 8; mi++)
#pragma unroll
            for (int r = 0; r < 4; r++) {
                int m = m0 + (wr << 7) + (mi << 4) + ((lane >> 4) << 2) + r;
                u16* row = C + (size_t)m * N + colbase;
#pragma unroll
                for (int ni = 0; ni < 4; ni++) row[ni << 4] = bf16u(acc[mi][ni][r]);
            }
    }
}

// ---------------- axial attention, one (line, head) per block ----------------
__global__ __launch_bounds__(256) void axial_attn(
    const u16* __restrict__ qkv, const float* __restrict__ mask,
    u16* __restrict__ cat, int hmode)
{
    __shared__ u16 Kl[128 * 64];    // XOR-swizzled 16B chunks (^ row&7)
    __shared__ u16 VT[64 * 128];    // V^T, swizzled (^ d&15)
    __shared__ u16 Pl[128 * 128];   // P (q-major), swizzled (^ q&15)
    const int orig = blockIdx.x;
    const int b = (orig & 7) * 256 + (orig >> 3);   // nwg = 2048
    const int a = b >> 4, hd = b & 15;
    const int tid = threadIdx.x, wid = tid >> 6, lane = tid & 63;
    const int tmul = hmode ? 128 : 1;
    const int tadd = hmode ? a : (a << 7);
    const size_t hoff = (size_t)hd << 6;

#pragma unroll
    for (int c = 0; c < 4; c++) {
        int row = (wid << 5) + (c << 3) + (lane >> 3);
        int sc = (lane & 7) ^ (row & 7);
        gl_lds16(qkv + (size_t)(row * tmul + tadd) * 3072 + 1024 + hoff + (sc << 3),
                 &Kl[((wid << 5) + (c << 3)) << 6]);
    }
#pragma unroll
    for (int i = 0; i < 4; i++) {
        int cid = tid + (i << 8);
        int j = cid >> 3;
        int d0 = (cid & 7) << 3;
        uint4 raw = *(const uint4*)(qkv + (size_t)(j * tmul + tadd) * 3072 + 2048 + hoff + d0);
        const u16* e = (const u16*)&raw;
#pragma unroll
        for (int t = 0; t < 8; t++) {
            int d = d0 + t;
            VT[(d << 7) + (((j >> 3) ^ (d & 15)) << 3) + (j & 7)] = e[t];
        }
    }
    bf16x8 aq[2][2];
#pragma unroll
    for (int qt = 0; qt < 2; qt++)
#pragma unroll
        for (int ks = 0; ks < 2; ks++) {
            int row = (wid << 5) + (qt << 4) + (lane & 15);
            aq[qt][ks] = *(const bf16x8*)(qkv + (size_t)(row * tmul + tadd) * 3072 + hoff
                                          + (ks << 5) + ((lane >> 4) << 3));
        }
    __syncthreads();

    f32x4 S[2][8] = {};
#pragma unroll
    for (int kt = 0; kt < 8; kt++) {
        bf16x8 bk[2];
#pragma unroll
        for (int ks = 0; ks < 2; ks++) {
            int row = (kt << 4) + (lane & 15);
            int ch = ((ks << 2) + (lane >> 4)) ^ (row & 7);
            bk[ks] = *(const bf16x8*)&Kl[(row << 6) + (ch << 3)];
        }
#pragma unroll
        for (int qt = 0; qt < 2; qt++) {
            S[qt][kt] = __builtin_amdgcn_mfma_f32_16x16x32_bf16(aq[qt][0], bk[0], S[qt][kt], 0, 0, 0);
            S[qt][kt] = __builtin_amdgcn_mfma_f32_16x16x32_bf16(aq[qt][1], bk[1], S[qt][kt], 0, 0, 0);
        }
    }

    const float scale = 0.03125f;   // 1/sqrt(1024)
#pragma unroll
    for (int qt = 0; qt < 2; qt++) {
#pragma unroll
        for (int r = 0; r < 4; r++) {
            int qrow = (wid << 5) + (qt << 4) + ((lane >> 4) << 2) + r;
            const float* mrow = mask + (hmode ? (a << 7) : (qrow << 7));
            float mx = -1e30f;
#pragma unroll
            for (int kt = 0; kt < 8; kt++) {
                float sv = fmaf(S[qt][kt][r], scale, mrow[(kt << 4) + (lane & 15)]);
                S[qt][kt][r] = sv;
                mx = fmaxf(mx, sv);
            }
            mx = fmaxf(mx, __shfl_xor(mx, 1));
            mx = fmaxf(mx, __shfl_xor(mx, 2));
            mx = fmaxf(mx, __shfl_xor(mx, 4));
            mx = fmaxf(mx, __shfl_xor(mx, 8));
            float sum = 0.f;
#pragma unroll
            for (int kt = 0; kt < 8; kt++) {
                float p = __expf(S[qt][kt][r] - mx);
                S[qt][kt][r] = p;
                sum += p;
            }
            sum += __shfl_xor(sum, 1);
            sum += __shfl_xor(sum, 2);
            sum += __shfl_xor(sum, 4);
            sum += __shfl_xor(sum, 8);
            float rinv = 1.0f / sum;
#pragma unroll
            for (int kt = 0; kt < 8; kt++) {
                int kcol = (kt << 4) + (lane & 15);
                int ch = (kcol >> 3) ^ (qrow & 15);
                Pl[(qrow << 7) + (ch << 3) + (kcol & 7)] = bf16u(S[qt][kt][r] * rinv);
            }
        }
    }
    __syncthreads();

    f32x4 O[4][2] = {};
#pragma unroll
    for (int ks = 0; ks < 4; ks++) {
        bf16x8 av[4], bp[2];
#pragma unroll
        for (int dt = 0; dt < 4; dt++) {
            int drow = (dt << 4) + (lane & 15);
            int ch = ((ks << 2) + (lane >> 4)) ^ (drow & 15);
            av[dt] = *(const bf16x8*)&VT[(drow << 7) + (ch << 3)];
        }
#pragma unroll
        for (int qt = 0; qt < 2; qt++) {
            int qrow = (wid << 5) + (qt << 4) + (lane & 15);
            int ch = ((ks << 2) + (lane >> 4)) ^ (qrow & 15);
            bp[qt] = *(const bf16x8*)&Pl[(qrow << 7) + (ch << 3)];
        }
#pragma unroll
        for (int dt = 0; dt < 4; dt++)
#pragma unroll
            for (int qt = 0; qt < 2; qt++)
                O[dt][qt] = __builtin_amdgcn_mfma_f32_16x16x32_bf16(av[dt], bp[qt], O[dt][qt], 0, 0, 0);
    }

    const int cbase = (hmode ? 1024 : 0) + (hd << 6);
#pragma unroll
    for (int dt = 0; dt < 4; dt++)
#pragma unroll
        for (int qt = 0; qt < 2; qt++) {
            int qrow = (wid << 5) + (qt << 4) + (lane & 15);
            int d0 = (dt << 4) + ((lane >> 4) << 2);
            size_t base = ((size_t)(qrow * tmul + tadd) << 11) + cbase + d0;
            ushort4 pk;
            pk.x = bf16u(O[dt][qt][0]);
            pk.y = bf16u(O[dt][qt][1]);
            pk.z = bf16u(O[dt][qt][2]);
            pk.w = bf16u(O[dt][qt][3]);
            *(ushort4*)(cat + base) = pk;
        }
}

extern "C" void kernel_launch(void* const* d_in, const int* in_sizes, int n_in,
                              void* d_out, int out_size, void* d_ws, size_t ws_size,
                              hipStream_t stream)
{
    (void)in_sizes; (void)n_in; (void)out_size; (void)ws_size;
    const float* hidden = (const float*)d_in[0];
    const float* mask   = (const float*)d_in[1];
    const float* cosp   = (const float*)d_in[2];
    const float* sinp   = (const float*)d_in[3];
    const float* Wq     = (const float*)d_in[4];
    const float* Wk     = (const float*)d_in[5];
    const float* Wv     = (const float*)d_in[6];
    const float* Wo     = (const float*)d_in[7];

    char* ws = (char*)d_ws;
    u16* Xb    = (u16*)(ws);                  // 33,554,432 B
    u16* WqkvT = (u16*)(ws + 33554432);       //  6,291,456 B
    u16* cat   = (u16*)(ws);                  // 67,108,864 B (reuse, stream-ordered)
    u16* WoT   = (u16*)(ws + 67108864);       //  4,194,304 B
    u16* qkvb  = (u16*)(ws + 71303168);       // 100,663,296 B

    cvt_x_kernel<<<16384, 256, 0, stream>>>((const float4*)hidden, (ushort4*)Xb, 4194304);

    transp_kernel<<<dim3(32, 32), 256, 0, stream>>>(Wq, WqkvT,               1024, 1024);
    transp_kernel<<<dim3(32, 32), 256, 0, stream>>>(Wk, WqkvT + 1024 * 1024, 1024, 1024);
    transp_kernel<<<dim3(32, 32), 256, 0, stream>>>(Wv, WqkvT + 2048 * 1024, 1024, 1024);
    transp_kernel<<<dim3(32, 64), 256, 0, stream>>>(Wo, WoT, 2048, 1024);

    // fused QKV projection + RoPE: [16384,1024] x [1024,3072]
    gemm8<<<dim3(12, 64), 512, 0, stream>>>(Xb, WqkvT, qkvb, cosp, sinp, 16384, 3072, 1024, 1);

    axial_attn<<<2048, 256, 0, stream>>>(qkvb, mask, cat, 0);
    axial_attn<<<2048, 256, 0, stream>>>(qkvb, mask, cat, 1);

    // output projection: [16384,2048] x [2048,1024] -> fp32
    gemm8<<<dim3(4, 64), 512, 0, stream>>>(cat, WoT, d_out, nullptr, nullptr, 16384, 1024, 2048, 2);
}

// Round 7
// 316.941 us; speedup vs baseline: 1.4753x; 1.4753x over previous
//
#include <hip/hip_runtime.h>

typedef unsigned short u16;
typedef unsigned int   u32;
typedef __bf16 bf16;
typedef bf16  bf16x8 __attribute__((ext_vector_type(8)));
typedef float f32x4  __attribute__((ext_vector_type(4)));

__device__ __forceinline__ u16 bf16u(float f) {
    u32 x = __builtin_bit_cast(u32, f);
    x += 0x7fffu + ((x >> 16) & 1u);   // RNE
    return (u16)(x >> 16);
}

__device__ __forceinline__ void gl_lds16(const void* g, void* l) {
    __builtin_amdgcn_global_load_lds(
        (const __attribute__((address_space(1))) u32*)g,
        (__attribute__((address_space(3))) u32*)l, 16, 0, 0);
}

// ---------------- fp32 -> bf16 convert (vectorized) ----------------
__global__ __launch_bounds__(256) void cvt_x_kernel(const float4* __restrict__ in,
                                                    ushort4* __restrict__ out, int n4) {
    int i = blockIdx.x * 256 + threadIdx.x;
    if (i >= n4) return;
    float4 f = in[i];
    ushort4 o;
    o.x = bf16u(f.x); o.y = bf16u(f.y); o.z = bf16u(f.z); o.w = bf16u(f.w);
    out[i] = o;
}

// ------- all 4 weight transposes in one kernel (fp32 W -> bf16 W^T) --------
__global__ __launch_bounds__(256) void transp_all(
    const float* __restrict__ Wq, const float* __restrict__ Wk,
    const float* __restrict__ Wv, const float* __restrict__ Wo,
    u16* __restrict__ WqkvT, u16* __restrict__ WoT)
{
    const int z = blockIdx.z;
    const float* W; u16* WT; int rows, cols;
    if (z < 3) {
        if (blockIdx.y >= 32) return;
        W = (z == 0) ? Wq : (z == 1) ? Wk : Wv;
        WT = WqkvT + (size_t)z * 1024 * 1024;
        rows = 1024; cols = 1024;
    } else {
        W = Wo; WT = WoT; rows = 2048; cols = 1024;
    }
    __shared__ float t[32][33];
    int bx = blockIdx.x * 32, by = blockIdx.y * 32;
    int x = threadIdx.x & 31, y = threadIdx.x >> 5;
#pragma unroll
    for (int i = 0; i < 32; i += 8)
        t[y + i][x] = W[(size_t)(by + y + i) * cols + bx + x];
    __syncthreads();
#pragma unroll
    for (int i = 0; i < 32; i += 8)
        WT[(size_t)(bx + y + i) * rows + by + x] = bf16u(t[x][y + i]);
}

// ========== 256x256 GEMM, BK=32, 3-buffer, 1 fat phase per K-tile ==========
// C[M][N] = A[M][K]*BT[N][K]^T. 512 thr = 8 waves (2M x 4N), wave 128x64.
// LDS: 3 bufs x (A[256][32] + B[256][32]) x 2B = 96 KB.
// Phase t: {12 ds_read (frags of tile t) | stage tile t+2 -> buf[(t+2)%3]}
//          BAR; 32 MFMA (setprio); publish t+1 via counted vmcnt(4); BAR; SB0.
// Stage queue has ONE stage point per phase -> vmcnt order == tile order.
// Chunk swizzle (rows of 4x16B chunks): phys = logical ^ ((row>>1)&3);
// inverse-applied on the global source (linear gl_lds dest), forward on reads.
#define BAR   __builtin_amdgcn_s_barrier()
#define SB0   __builtin_amdgcn_sched_barrier(0)
#define VM4   asm volatile("s_waitcnt vmcnt(4)" ::: "memory")
#define VM0   asm volatile("s_waitcnt vmcnt(0)" ::: "memory")

__global__ __launch_bounds__(512, 2) void gemm8(
    const u16* __restrict__ A, const u16* __restrict__ BT, void* __restrict__ Cout,
    const float* __restrict__ cosp, const float* __restrict__ sinp,
    int M, int N, int K, int mode)
{
    __shared__ u16 Ld[3][16384];   // per buf: A @0 (8192 u16), B @8192
    const int tid = threadIdx.x;
    const int wid = tid >> 6, lane = tid & 63;
    const int nx = gridDim.x;
    const int nwg = nx * gridDim.y;
    const int orig = blockIdx.y * nx + blockIdx.x;
    const int vid = (orig & 7) * (nwg >> 3) + (orig >> 3);
    const int m0 = (vid / nx) << 8, n0 = (vid % nx) << 8;
    const int wr = wid >> 2, wc = wid & 3;

    // ---- staging descriptors: 4 gl_lds per thread per K-tile ----
    const int srow = tid >> 2;                     // row 0..127
    const int sl = (tid & 3) ^ ((srow >> 1) & 3);  // inverse-swizzled chunk
    const u16* aS0 = A + (size_t)(m0 + srow) * K + (sl << 3);
    const u16* aS1 = aS0 + (size_t)128 * K;
    const u16* bS0 = BT + (size_t)(n0 + srow) * K + (sl << 3);
    const u16* bS1 = bS0 + (size_t)128 * K;
    const int wdb = wid << 9;                      // wave-uniform dest (u16)
    const int nt = K >> 5;

#define STAGE(T, B_) do { if ((T) < nt) { size_t _ko = (size_t)(T) << 5; \
        gl_lds16(aS0 + _ko, &Ld[B_][wdb]); \
        gl_lds16(aS1 + _ko, &Ld[B_][4096 + wdb]); \
        gl_lds16(bS0 + _ko, &Ld[B_][8192 + wdb]); \
        gl_lds16(bS1 + _ko, &Ld[B_][12288 + wdb]); } } while (0)

    // frag reads: row = base + frag*16 + (lane&15); chunk = (lane>>4)^((lane>>1)&3)
    const int phys = ((lane >> 4) ^ ((lane >> 1) & 3)) << 3;   // u16 offset
    const int raw = ((wr << 7) + (lane & 15)) << 5;            // A row base (u16)
    const int rbw = (((wc << 6) + (lane & 15)) << 5) + 8192;   // B row base (u16)

    f32x4 acc[8][4] = {};

    STAGE(0, 0); STAGE(1, 1);
    VM4;                       // tile 0 landed; tile 1 (4 loads) in flight
    BAR; SB0;

    int b = 0, bs = 2;
    for (int t = 0; t < nt; ++t) {
        const u16* Lb = &Ld[b][0];
        bf16x8 fa[8], fb[4];
#pragma unroll
        for (int mi = 0; mi < 8; mi++)
            fa[mi] = *(const bf16x8*)&Lb[raw + (mi << 9) + phys];
#pragma unroll
        for (int ni = 0; ni < 4; ni++)
            fb[ni] = *(const bf16x8*)&Lb[rbw + (ni << 9) + phys];
        STAGE(t + 2, bs);
        BAR;
        __builtin_amdgcn_s_setprio(1);
#pragma unroll
        for (int mi = 0; mi < 8; mi++)
#pragma unroll
            for (int ni = 0; ni < 4; ni++)
                acc[mi][ni] = __builtin_amdgcn_mfma_f32_16x16x32_bf16(
                    fa[mi], fb[ni], acc[mi][ni], 0, 0, 0);
        __builtin_amdgcn_s_setprio(0);
        if (t + 2 < nt) { VM4; } else { VM0; }   // publish tile t+1
        BAR; SB0;
        b = (b == 2) ? 0 : b + 1;
        bs = (bs == 2) ? 0 : bs + 1;
    }
#undef STAGE

    const int colbase = n0 + (wc << 6) + (lane & 15);
    if (mode == 2) {
        float* C = (float*)Cout;
#pragma unroll
        for (int mi = 0; mi < 8; mi++)
#pragma unroll
            for (int r = 0; r < 4; r++) {
                int m = m0 + (wr << 7) + (mi << 4) + ((lane >> 4) << 2) + r;
                float* row = C + (size_t)m * N + colbase;
#pragma unroll
                for (int ni = 0; ni < 4; ni++) row[ni << 4] = acc[mi][ni][r];
            }
    } else if (n0 < 2048) {                   // fused QKV: RoPE region (Q and K)
        u16* C = (u16*)Cout;
#pragma unroll
        for (int mi = 0; mi < 8; mi++)
#pragma unroll
            for (int r = 0; r < 4; r++) {
                int m = m0 + (wr << 7) + (mi << 4) + ((lane >> 4) << 2) + r;
                const float* cb = cosp + ((size_t)m << 6);
                const float* sb = sinp + ((size_t)m << 6);
                u16* row = C + (size_t)m * N + colbase;
#pragma unroll
                for (int ni = 0; ni < 4; ni++) {
                    int d = (ni << 4) + (lane & 15);   // head-dim pos (0..63)
                    float c = cb[d], s = sb[d];
                    float v0 = acc[mi][ni][r];
                    float vr = acc[mi][ni ^ 2][r];     // d +/- 32 partner
                    float o = fmaf(v0, c, (ni < 2 ? -vr : vr) * s);
                    row[ni << 4] = bf16u(o);
                }
            }
    } else {                                  // V region: plain bf16
        u16* C = (u16*)Cout;
#pragma unroll
        for (int mi = 0; mi < 8; mi++)
#pragma unroll
            for (int r = 0; r < 4; r++) {
                int m = m0 + (wr << 7) + (mi << 4) + ((lane >> 4) << 2) + r;
                u16* row = C + (size_t)m * N + colbase;
#pragma unroll
                for (int ni = 0; ni < 4; ni++) row[ni << 4] = bf16u(acc[mi][ni][r]);
            }
    }
}

// ------- axial attention, both passes in one launch (4096 blocks) ----------
// qkv: (16384 x 3072) bf16 [q|k|v]. blocks [0,2048) = width, [2048,4096) = height.
__global__ __launch_bounds__(256) void axial_attn(
    const u16* __restrict__ qkv, const float* __restrict__ mask,
    u16* __restrict__ cat)
{
    __shared__ u16 Kl[128 * 64];    // XOR-swizzled 16B chunks (^ row&7)
    __shared__ u16 VT[64 * 128];    // V^T, swizzled (^ d&15)
    __shared__ u16 Pl[128 * 128];   // P (q-major), swizzled (^ q&15)
    const int hmode = blockIdx.x >> 11;
    const int o2 = blockIdx.x & 2047;
    const int b = (o2 & 7) * 256 + (o2 >> 3);   // per-half XCD chunk swizzle
    const int a = b >> 4, hd = b & 15;
    const int tid = threadIdx.x, wid = tid >> 6, lane = tid & 63;
    const int tmul = hmode ? 128 : 1;
    const int tadd = hmode ? a : (a << 7);
    const size_t hoff = (size_t)hd << 6;

#pragma unroll
    for (int c = 0; c < 4; c++) {
        int row = (wid << 5) + (c << 3) + (lane >> 3);
        int sc = (lane & 7) ^ (row & 7);
        gl_lds16(qkv + (size_t)(row * tmul + tadd) * 3072 + 1024 + hoff + (sc << 3),
                 &Kl[((wid << 5) + (c << 3)) << 6]);
    }
#pragma unroll
    for (int i = 0; i < 4; i++) {
        int cid = tid + (i << 8);
        int j = cid >> 3;
        int d0 = (cid & 7) << 3;
        uint4 raw = *(const uint4*)(qkv + (size_t)(j * tmul + tadd) * 3072 + 2048 + hoff + d0);
        const u16* e = (const u16*)&raw;
#pragma unroll
        for (int t = 0; t < 8; t++) {
            int d = d0 + t;
            VT[(d << 7) + (((j >> 3) ^ (d & 15)) << 3) + (j & 7)] = e[t];
        }
    }
    bf16x8 aq[2][2];
#pragma unroll
    for (int qt = 0; qt < 2; qt++)
#pragma unroll
        for (int ks = 0; ks < 2; ks++) {
            int row = (wid << 5) + (qt << 4) + (lane & 15);
            aq[qt][ks] = *(const bf16x8*)(qkv + (size_t)(row * tmul + tadd) * 3072 + hoff
                                          + (ks << 5) + ((lane >> 4) << 3));
        }
    __syncthreads();

    f32x4 S[2][8] = {};
#pragma unroll
    for (int kt = 0; kt < 8; kt++) {
        bf16x8 bk[2];
#pragma unroll
        for (int ks = 0; ks < 2; ks++) {
            int row = (kt << 4) + (lane & 15);
            int ch = ((ks << 2) + (lane >> 4)) ^ (row & 7);
            bk[ks] = *(const bf16x8*)&Kl[(row << 6) + (ch << 3)];
        }
#pragma unroll
        for (int qt = 0; qt < 2; qt++) {
            S[qt][kt] = __builtin_amdgcn_mfma_f32_16x16x32_bf16(aq[qt][0], bk[0], S[qt][kt], 0, 0, 0);
            S[qt][kt] = __builtin_amdgcn_mfma_f32_16x16x32_bf16(aq[qt][1], bk[1], S[qt][kt], 0, 0, 0);
        }
    }

    const float scale = 0.03125f;   // 1/sqrt(1024)
#pragma unroll
    for (int qt = 0; qt < 2; qt++) {
#pragma unroll
        for (int r = 0; r < 4; r++) {
            int qrow = (wid << 5) + (qt << 4) + ((lane >> 4) << 2) + r;
            const float* mrow = mask + (hmode ? (a << 7) : (qrow << 7));
            float mx = -1e30f;
#pragma unroll
            for (int kt = 0; kt < 8; kt++) {
                float sv = fmaf(S[qt][kt][r], scale, mrow[(kt << 4) + (lane & 15)]);
                S[qt][kt][r] = sv;
                mx = fmaxf(mx, sv);
            }
            mx = fmaxf(mx, __shfl_xor(mx, 1));
            mx = fmaxf(mx, __shfl_xor(mx, 2));
            mx = fmaxf(mx, __shfl_xor(mx, 4));
            mx = fmaxf(mx, __shfl_xor(mx, 8));
            float sum = 0.f;
#pragma unroll
            for (int kt = 0; kt < 8; kt++) {
                float p = __expf(S[qt][kt][r] - mx);
                S[qt][kt][r] = p;
                sum += p;
            }
            sum += __shfl_xor(sum, 1);
            sum += __shfl_xor(sum, 2);
            sum += __shfl_xor(sum, 4);
            sum += __shfl_xor(sum, 8);
            float rinv = 1.0f / sum;
#pragma unroll
            for (int kt = 0; kt < 8; kt++) {
                int kcol = (kt << 4) + (lane & 15);
                int ch = (kcol >> 3) ^ (qrow & 15);
                Pl[(qrow << 7) + (ch << 3) + (kcol & 7)] = bf16u(S[qt][kt][r] * rinv);
            }
        }
    }
    __syncthreads();

    f32x4 O[4][2] = {};
#pragma unroll
    for (int ks = 0; ks < 4; ks++) {
        bf16x8 av[4], bp[2];
#pragma unroll
        for (int dt = 0; dt < 4; dt++) {
            int drow = (dt << 4) + (lane & 15);
            int ch = ((ks << 2) + (lane >> 4)) ^ (drow & 15);
            av[dt] = *(const bf16x8*)&VT[(drow << 7) + (ch << 3)];
        }
#pragma unroll
        for (int qt = 0; qt < 2; qt++) {
            int qrow = (wid << 5) + (qt << 4) + (lane & 15);
            int ch = ((ks << 2) + (lane >> 4)) ^ (qrow & 15);
            bp[qt] = *(const bf16x8*)&Pl[(qrow << 7) + (ch << 3)];
        }
#pragma unroll
        for (int dt = 0; dt < 4; dt++)
#pragma unroll
            for (int qt = 0; qt < 2; qt++)
                O[dt][qt] = __builtin_amdgcn_mfma_f32_16x16x32_bf16(av[dt], bp[qt], O[dt][qt], 0, 0, 0);
    }

    const int cbase = (hmode ? 1024 : 0) + (hd << 6);
#pragma unroll
    for (int dt = 0; dt < 4; dt++)
#pragma unroll
        for (int qt = 0; qt < 2; qt++) {
            int qrow = (wid << 5) + (qt << 4) + (lane & 15);
            int d0 = (dt << 4) + ((lane >> 4) << 2);
            size_t base = ((size_t)(qrow * tmul + tadd) << 11) + cbase + d0;
            ushort4 pk;
            pk.x = bf16u(O[dt][qt][0]);
            pk.y = bf16u(O[dt][qt][1]);
            pk.z = bf16u(O[dt][qt][2]);
            pk.w = bf16u(O[dt][qt][3]);
            *(ushort4*)(cat + base) = pk;
        }
}

extern "C" void kernel_launch(void* const* d_in, const int* in_sizes, int n_in,
                              void* d_out, int out_size, void* d_ws, size_t ws_size,
                              hipStream_t stream)
{
    (void)in_sizes; (void)n_in; (void)out_size; (void)ws_size;
    const float* hidden = (const float*)d_in[0];
    const float* mask   = (const float*)d_in[1];
    const float* cosp   = (const float*)d_in[2];
    const float* sinp   = (const float*)d_in[3];
    const float* Wq     = (const float*)d_in[4];
    const float* Wk     = (const float*)d_in[5];
    const float* Wv     = (const float*)d_in[6];
    const float* Wo     = (const float*)d_in[7];

    char* ws = (char*)d_ws;
    u16* Xb    = (u16*)(ws);                  // 33,554,432 B
    u16* WqkvT = (u16*)(ws + 33554432);       //  6,291,456 B
    u16* cat   = (u16*)(ws);                  // 67,108,864 B (reuse, stream-ordered)
    u16* WoT   = (u16*)(ws + 67108864);       //  4,194,304 B
    u16* qkvb  = (u16*)(ws + 71303168);       // 100,663,296 B

    cvt_x_kernel<<<16384, 256, 0, stream>>>((const float4*)hidden, (ushort4*)Xb, 4194304);
    transp_all<<<dim3(32, 64, 4), 256, 0, stream>>>(Wq, Wk, Wv, Wo, WqkvT, WoT);

    // fused QKV projection + RoPE: [16384,1024] x [1024,3072]
    gemm8<<<dim3(12, 64), 512, 0, stream>>>(Xb, WqkvT, qkvb, cosp, sinp, 16384, 3072, 1024, 1);

    axial_attn<<<4096, 256, 0, stream>>>(qkvb, mask, cat);

    // output projection: [16384,2048] x [2048,1024] -> fp32
    gemm8<<<dim3(4, 64), 512, 0, stream>>>(cat, WoT, d_out, nullptr, nullptr, 16384, 1024, 2048, 2);
}